// Round 3
// baseline (291.702 us; speedup 1.0000x reference)
//
#include <hip/hip_runtime.h>

// SwitchTransformers sparse MLP (top-1 MoE), MI355X/gfx950.
// Round 2: fix A-staging (was covering only half of each 64B row -> NaN
// from uninitialized LDS in the g=1,3 A-fragments). fp64 router + bf16
// MFMA expert GEMMs (128x128 tile, BK=32, 2-barrier loop).

typedef __attribute__((ext_vector_type(4))) float f32x4;
typedef __attribute__((ext_vector_type(8))) short short8;
typedef __attribute__((ext_vector_type(4))) short short4v;
typedef unsigned short ushort_t;
typedef unsigned int uint32;

#define DEVFN static __device__ __forceinline__

constexpr int NTOK = 4096;   // B*S
constexpr int DM   = 768;    // d_model
constexpr int DF   = 3072;   // d_ff
constexpr int NE   = 8;      // experts
constexpr int TM   = 128;    // row tile (padding granule)
constexpr int MAXROWS  = NTOK + NE * TM;   // 5120
constexpr int MAXTILES = NTOK / TM + NE;   // 40
constexpr int BK   = 32;
constexpr int KQS  = 640;    // B_lds stride per 4-k group (128*4 + pad 128)

// meta layout (ints): [0..7] counts, [8..15] cursor, [16..23] seg_end,
// [24] nRowTiles, [64..103] tileExpert, [128..167] tileRow
DEVFN ushort_t f2bf(float f) {           // fp32 -> bf16 RNE (finite inputs)
  uint32 u = __float_as_uint(f);
  u += 0x7fffu + ((u >> 16) & 1u);
  return (ushort_t)(u >> 16);
}

__global__ void k_init(int* __restrict__ meta) {
  if (threadIdx.x < NE) meta[threadIdx.x] = 0;
}

// One wave per token: fp64 logits (argmax robustness), softmax top-1 prob.
__global__ __launch_bounds__(256) void k_router(
    const float* __restrict__ X, const float* __restrict__ Wr,
    float* __restrict__ out_logits, float* __restrict__ out_idx,
    int* __restrict__ expert_of, float* __restrict__ prob,
    int* __restrict__ meta) {
  int wid = threadIdx.x >> 6, lane = threadIdx.x & 63;
  int t = blockIdx.x * 4 + wid;
  const float* xrow = X + (size_t)t * DM;
  double acc[NE];
#pragma unroll
  for (int e = 0; e < NE; e++) acc[e] = 0.0;
  for (int d0 = 0; d0 < DM; d0 += 64) {
    int d = d0 + lane;
    float x = xrow[d];
    const float4* w4 = (const float4*)(Wr + (size_t)d * NE);
    float4 wa = w4[0], wb = w4[1];
    acc[0] += (double)x * wa.x; acc[1] += (double)x * wa.y;
    acc[2] += (double)x * wa.z; acc[3] += (double)x * wa.w;
    acc[4] += (double)x * wb.x; acc[5] += (double)x * wb.y;
    acc[6] += (double)x * wb.z; acc[7] += (double)x * wb.w;
  }
#pragma unroll
  for (int e = 0; e < NE; e++) {
#pragma unroll
    for (int s = 32; s > 0; s >>= 1) acc[e] += __shfl_xor(acc[e], s);
  }
#pragma unroll
  for (int e = 0; e < NE; e++)      // static indexing (avoid scratch)
    if (lane == e) out_logits[(size_t)t * NE + e] = (float)acc[e];
  if (lane == 0) {
    double m = acc[0]; int idx = 0;
#pragma unroll
    for (int e = 1; e < NE; e++) if (acc[e] > m) { m = acc[e]; idx = e; }
    double s = 0.0;
#pragma unroll
    for (int e = 0; e < NE; e++) s += exp(acc[e] - m);
    out_idx[t] = (float)idx;
    expert_of[t] = idx;
    prob[t] = (float)(1.0 / s);
    atomicAdd(&meta[idx], 1);
  }
}

// Single-thread scan: padded segment starts, seg_end, tile table.
__global__ void k_scan(int* __restrict__ meta) {
  if (threadIdx.x != 0 || blockIdx.x != 0) return;
  int pos = 0, nt = 0;
  for (int e = 0; e < NE; e++) {
    int c = meta[e];
    meta[8 + e]  = pos;        // cursor start
    meta[16 + e] = pos + c;    // seg_end (valid rows)
    int tiles = (c + TM - 1) / TM;
    for (int i = 0; i < tiles; i++) { meta[64 + nt] = e; meta[128 + nt] = pos + i * TM; nt++; }
    pos += tiles * TM;
  }
  meta[24] = nt;
}

// Gather tokens into expert-sorted bf16 buffer Xg; record perm + prob.
__global__ __launch_bounds__(256) void k_gather(
    const float* __restrict__ X, const int* __restrict__ expert_of,
    const float* __restrict__ prob, int* __restrict__ meta,
    int* __restrict__ perm, float* __restrict__ prob_g,
    ushort_t* __restrict__ Xg) {
  int wid = threadIdx.x >> 6, lane = threadIdx.x & 63;
  int t = blockIdx.x * 4 + wid;
  int e = expert_of[t];
  int pos = 0;
  if (lane == 0) {
    pos = atomicAdd(&meta[8 + e], 1);
    perm[pos] = t;
    prob_g[pos] = prob[t];
  }
  pos = __shfl(pos, 0);
  const float2* s2 = (const float2*)(X + (size_t)t * DM);
  uint32* d2 = (uint32*)(Xg + (size_t)pos * DM);
#pragma unroll
  for (int i = 0; i < DM / 128; i++) {
    float2 v = s2[i * 64 + lane];
    d2[i * 64 + lane] = (uint32)f2bf(v.x) | ((uint32)f2bf(v.y) << 16);
  }
}

// 128x128 tile GEMM, 4 waves (each 64x64 = 4x4 fragments of 16x16x32 bf16).
// A: bf16 rows (gathered). B: fp32 expert weights [KDIM][LDB], converted to
// bf16 during staging with a 4x4 in-register transpose into an interleaved
// padded LDS layout: elem(k,n) = (k>>2)*KQS + n*4 + (n>>2)*4 + (k&3).
// FIRST: H = relu(A*B) stored bf16.  !FIRST: out[perm[r]] = prob*(A*B).
template <int KDIM, int LDB, bool FIRST>
__global__ __launch_bounds__(256) void k_gemm(
    const ushort_t* __restrict__ A, const float* __restrict__ Bw,
    const int* __restrict__ meta, ushort_t* __restrict__ Hout,
    const int* __restrict__ perm, const float* __restrict__ prob_g,
    float* __restrict__ Yout) {
  __shared__ short A_lds[128 * BK];
  __shared__ short B_lds[8 * KQS];

  int bt = blockIdx.x;               // row-tile (x-major: blocks sharing a
  if (bt >= meta[24]) return;        //  B column panel are contiguous -> L2)
  int e    = meta[64 + bt];
  int row0 = meta[128 + bt];
  int n0   = blockIdx.y * 128;

  int tid = threadIdx.x;
  int lane = tid & 63;
  int wid = tid >> 6;
  int wr = wid >> 1, wc = wid & 1;

  // A staging: 2 threads/row, each loads 32B -> full 64B (32 bf16) row.
  const ushort_t* aSrc = A + (size_t)(row0 + (tid >> 1)) * KDIM + (tid & 1) * 16;
  short* aDst = &A_lds[(tid >> 1) * BK + (tid & 1) * 16];
  int kq = tid >> 5, nb = tid & 31;
  const float* bSrc = Bw + (size_t)e * KDIM * LDB + (size_t)kq * 4 * LDB + n0 + nb * 4;

  f32x4 acc[4][4];
#pragma unroll
  for (int m = 0; m < 4; m++)
#pragma unroll
    for (int c = 0; c < 4; c++)
      acc[m][c] = (f32x4){0.f, 0.f, 0.f, 0.f};

  for (int k0 = 0; k0 < KDIM; k0 += BK) {
    __syncthreads();
    // stage A: two 16B chunks per thread (128 rows x 64B total)
    *(short8*)aDst       = *(const short8*)aSrc;
    *(short8*)(aDst + 8) = *(const short8*)(aSrc + 8);
    // stage B: 4x4 fp32 micro-tile, convert, transpose into interleaved LDS
    float4 bv0 = *(const float4*)(bSrc);
    float4 bv1 = *(const float4*)(bSrc + LDB);
    float4 bv2 = *(const float4*)(bSrc + 2 * (size_t)LDB);
    float4 bv3 = *(const float4*)(bSrc + 3 * (size_t)LDB);
#pragma unroll
    for (int nn = 0; nn < 4; nn++) {
      int n = nb * 4 + nn;
      short4v pk;
      pk.x = (short)f2bf(((const float*)&bv0)[nn]);
      pk.y = (short)f2bf(((const float*)&bv1)[nn]);
      pk.z = (short)f2bf(((const float*)&bv2)[nn]);
      pk.w = (short)f2bf(((const float*)&bv3)[nn]);
      *(short4v*)&B_lds[kq * KQS + n * 4 + (n >> 2) * 4] = pk;
    }
    __syncthreads();

    short8 af[4];
#pragma unroll
    for (int m = 0; m < 4; m++) {
      int row = wr * 64 + m * 16 + (lane & 15);
      af[m] = *(const short8*)&A_lds[row * BK + (lane >> 4) * 8];
    }
#pragma unroll
    for (int c = 0; c < 4; c++) {
      int n = wc * 64 + c * 16 + (lane & 15);
      int g = lane >> 4;
      short4v lo = *(const short4v*)&B_lds[(2 * g) * KQS + n * 4 + (n >> 2) * 4];
      short4v hi = *(const short4v*)&B_lds[(2 * g + 1) * KQS + n * 4 + (n >> 2) * 4];
      short8 bf;
      bf[0] = lo.x; bf[1] = lo.y; bf[2] = lo.z; bf[3] = lo.w;
      bf[4] = hi.x; bf[5] = hi.y; bf[6] = hi.z; bf[7] = hi.w;
#pragma unroll
      for (int m = 0; m < 4; m++)
        acc[m][c] = __builtin_amdgcn_mfma_f32_16x16x32_bf16(af[m], bf, acc[m][c], 0, 0, 0);
    }
    aSrc += BK;
    bSrc += (size_t)BK * LDB;
  }

  // C/D layout (m89-verified): col = lane&15, row = (lane>>4)*4 + reg
  if constexpr (FIRST) {
#pragma unroll
    for (int m = 0; m < 4; m++) {
      int rowb = row0 + wr * 64 + m * 16 + (lane >> 4) * 4;
#pragma unroll
      for (int c = 0; c < 4; c++) {
        int col = n0 + wc * 64 + c * 16 + (lane & 15);
#pragma unroll
        for (int r = 0; r < 4; r++) {
          float v = acc[m][c][r];
          v = v > 0.f ? v : 0.f;                       // relu
          Hout[(size_t)(rowb + r) * LDB + col] = f2bf(v);
        }
      }
    }
  } else {
    int segEnd = meta[16 + e];
#pragma unroll
    for (int m = 0; m < 4; m++) {
#pragma unroll
      for (int r = 0; r < 4; r++) {
        int rg = row0 + wr * 64 + m * 16 + (lane >> 4) * 4 + r;
        if (rg < segEnd) {                             // mask pad rows
          int tok = perm[rg];
          float p = prob_g[rg];
#pragma unroll
          for (int c = 0; c < 4; c++) {
            int col = n0 + wc * 64 + c * 16 + (lane & 15);
            Yout[(size_t)tok * LDB + col] = p * acc[m][c][r];
          }
        }
      }
    }
  }
}

extern "C" void kernel_launch(void* const* d_in, const int* in_sizes, int n_in,
                              void* d_out, int out_size, void* d_ws, size_t ws_size,
                              hipStream_t stream) {
  const float* X  = (const float*)d_in[0];   // [4,1024,768]
  const float* Wr = (const float*)d_in[1];   // [768,8]
  const float* wi = (const float*)d_in[2];   // [8,768,3072]
  const float* wo = (const float*)d_in[3];   // [8,3072,768]

  float* out        = (float*)d_out;                 // [4096,768]
  float* out_logits = out + (size_t)NTOK * DM;       // [4096,8]
  float* out_idx    = out_logits + (size_t)NTOK * NE;// [4096] as float

  char* w = (char*)d_ws;
  int*      meta      = (int*)w;                        // 1 KiB
  int*      expert_of = (int*)(w + 1024);               // 16 KiB
  float*    prob      = (float*)(w + 1024 + 16384);     // 16 KiB
  int*      perm      = (int*)(w + 33792);              // 20 KiB
  float*    prob_g    = (float*)(w + 54272);            // 20 KiB
  ushort_t* Xg        = (ushort_t*)(w + 74752);         // 5120*768 bf16
  ushort_t* H         = Xg + (size_t)MAXROWS * DM;      // 5120*3072 bf16
  // total ws: ~39.4 MB

  k_init<<<1, 64, 0, stream>>>(meta);
  k_router<<<NTOK / 4, 256, 0, stream>>>(X, Wr, out_logits, out_idx,
                                         expert_of, prob, meta);
  k_scan<<<1, 64, 0, stream>>>(meta);
  k_gather<<<NTOK / 4, 256, 0, stream>>>(X, expert_of, prob, meta,
                                         perm, prob_g, Xg);
  k_gemm<DM, DF, true><<<dim3(MAXTILES, DF / 128), 256, 0, stream>>>(
      Xg, wi, meta, H, nullptr, nullptr, nullptr);
  k_gemm<DF, DM, false><<<dim3(MAXTILES, DM / 128), 256, 0, stream>>>(
      H, wo, meta, nullptr, perm, prob_g, out);
}

// Round 4
// 287.823 us; speedup vs baseline: 1.0135x; 1.0135x over previous
//
#include <hip/hip_runtime.h>

// SwitchTransformers sparse MLP (top-1 MoE), MI355X/gfx950.
// Round 3: pre-convert+transpose weights to bf16 [E][N][K]; both GEMMs
// rebuilt as m97-structure 128x128 tiles with global_load_lds (width 16)
// double-buffered 2-phase pipeline. Router/scan/gather unchanged.

typedef __attribute__((ext_vector_type(4))) float f32x4;
typedef __attribute__((ext_vector_type(8))) short short8;
typedef unsigned short ushort_t;
typedef unsigned int uint32;

#define DEVFN static __device__ __forceinline__

constexpr int NTOK = 4096;   // B*S
constexpr int DM   = 768;    // d_model
constexpr int DF   = 3072;   // d_ff
constexpr int NE   = 8;      // experts
constexpr int TM   = 128;    // row tile (padding granule)
constexpr int MAXROWS  = NTOK + NE * TM;   // 5120
constexpr int MAXTILES = NTOK / TM + NE;   // 40
constexpr int BK   = 32;

// meta layout (ints): [0..7] counts, [8..15] cursor, [16..23] seg_end,
// [24] nRowTiles, [64..103] tileExpert, [128..167] tileRow
DEVFN ushort_t f2bf(float f) {           // fp32 -> bf16 RNE (finite inputs)
  uint32 u = __float_as_uint(f);
  u += 0x7fffu + ((u >> 16) & 1u);
  return (ushort_t)(u >> 16);
}

DEVFN void gload_lds16(const void* g, void* l) {   // 16B/lane direct-to-LDS
  __builtin_amdgcn_global_load_lds(
      (const __attribute__((address_space(1))) void*)g,
      (__attribute__((address_space(3))) void*)l, 16, 0, 0);
}

__global__ void k_init(int* __restrict__ meta) {
  if (threadIdx.x < NE) meta[threadIdx.x] = 0;
}

// One wave per token: fp64 logits (argmax robustness), softmax top-1 prob.
__global__ __launch_bounds__(256) void k_router(
    const float* __restrict__ X, const float* __restrict__ Wr,
    float* __restrict__ out_logits, float* __restrict__ out_idx,
    int* __restrict__ expert_of, float* __restrict__ prob,
    int* __restrict__ meta) {
  int wid = threadIdx.x >> 6, lane = threadIdx.x & 63;
  int t = blockIdx.x * 4 + wid;
  const float* xrow = X + (size_t)t * DM;
  double acc[NE];
#pragma unroll
  for (int e = 0; e < NE; e++) acc[e] = 0.0;
  for (int d0 = 0; d0 < DM; d0 += 64) {
    int d = d0 + lane;
    float x = xrow[d];
    const float4* w4 = (const float4*)(Wr + (size_t)d * NE);
    float4 wa = w4[0], wb = w4[1];
    acc[0] += (double)x * wa.x; acc[1] += (double)x * wa.y;
    acc[2] += (double)x * wa.z; acc[3] += (double)x * wa.w;
    acc[4] += (double)x * wb.x; acc[5] += (double)x * wb.y;
    acc[6] += (double)x * wb.z; acc[7] += (double)x * wb.w;
  }
#pragma unroll
  for (int e = 0; e < NE; e++) {
#pragma unroll
    for (int s = 32; s > 0; s >>= 1) acc[e] += __shfl_xor(acc[e], s);
  }
#pragma unroll
  for (int e = 0; e < NE; e++)      // static indexing (avoid scratch)
    if (lane == e) out_logits[(size_t)t * NE + e] = (float)acc[e];
  if (lane == 0) {
    double m = acc[0]; int idx = 0;
#pragma unroll
    for (int e = 1; e < NE; e++) if (acc[e] > m) { m = acc[e]; idx = e; }
    double s = 0.0;
#pragma unroll
    for (int e = 0; e < NE; e++) s += exp(acc[e] - m);
    out_idx[t] = (float)idx;
    expert_of[t] = idx;
    prob[t] = (float)(1.0 / s);
    atomicAdd(&meta[idx], 1);
  }
}

// Single-thread scan: padded segment starts, seg_end, tile table.
__global__ void k_scan(int* __restrict__ meta) {
  if (threadIdx.x != 0 || blockIdx.x != 0) return;
  int pos = 0, nt = 0;
  for (int e = 0; e < NE; e++) {
    int c = meta[e];
    meta[8 + e]  = pos;        // cursor start
    meta[16 + e] = pos + c;    // seg_end (valid rows)
    int tiles = (c + TM - 1) / TM;
    for (int i = 0; i < tiles; i++) { meta[64 + nt] = e; meta[128 + nt] = pos + i * TM; nt++; }
    pos += tiles * TM;
  }
  meta[24] = nt;
}

// Gather tokens into expert-sorted bf16 buffer Xg; record perm + prob.
__global__ __launch_bounds__(256) void k_gather(
    const float* __restrict__ X, const int* __restrict__ expert_of,
    const float* __restrict__ prob, int* __restrict__ meta,
    int* __restrict__ perm, float* __restrict__ prob_g,
    ushort_t* __restrict__ Xg) {
  int wid = threadIdx.x >> 6, lane = threadIdx.x & 63;
  int t = blockIdx.x * 4 + wid;
  int e = expert_of[t];
  int pos = 0;
  if (lane == 0) {
    pos = atomicAdd(&meta[8 + e], 1);
    perm[pos] = t;
    prob_g[pos] = prob[t];
  }
  pos = __shfl(pos, 0);
  const float2* s2 = (const float2*)(X + (size_t)t * DM);
  uint32* d2 = (uint32*)(Xg + (size_t)pos * DM);
#pragma unroll
  for (int i = 0; i < DM / 128; i++) {
    float2 v = s2[i * 64 + lane];
    d2[i * 64 + lane] = (uint32)f2bf(v.x) | ((uint32)f2bf(v.y) << 16);
  }
}

// Convert + transpose: W [E][R][C] fp32 -> WT [E][C][R] bf16. 128x128 tiles.
__global__ __launch_bounds__(256) void k_convT(
    const float* __restrict__ W, ushort_t* __restrict__ WT, int R, int C) {
  __shared__ ushort_t T[128][136];          // +8 pad: 16B-aligned rows
  int e = blockIdx.z;
  int r0 = blockIdx.x * 128, c0 = blockIdx.y * 128;
  const float* src = W + ((size_t)e * R + r0) * C + c0;
  int t = threadIdx.x;
  int lr = t >> 1, cc = (t & 1) * 64;
#pragma unroll
  for (int j = 0; j < 16; j++) {
    float4 v = *(const float4*)(src + (size_t)lr * C + cc + j * 4);
    T[cc + j * 4 + 0][lr] = f2bf(v.x);
    T[cc + j * 4 + 1][lr] = f2bf(v.y);
    T[cc + j * 4 + 2][lr] = f2bf(v.z);
    T[cc + j * 4 + 3][lr] = f2bf(v.w);
  }
  __syncthreads();
  ushort_t* dst = WT + ((size_t)e * C + c0) * R + r0;
  int lc = t >> 1, rr = (t & 1) * 64;
#pragma unroll
  for (int j = 0; j < 8; j++)
    *(short8*)(dst + (size_t)lc * R + rr + j * 8) =
        *(const short8*)&T[lc][rr + j * 8];
}

// m97-structure GEMM: 128x128 tile, 4 waves (64x64 each, 4x4 frags of
// 16x16x32 bf16), BK=32, double-buffered global_load_lds staging.
// A: bf16 [rows][KDIM]. BT: bf16 [E][LDB][KDIM] (N-major, K contiguous).
// FIRST: H = relu(A*B) bf16.  !FIRST: out[perm[r]] = prob*(A*B) fp32.
template <int KDIM, int LDB, bool FIRST>
__global__ __launch_bounds__(256, 4) void k_gemm(
    const ushort_t* __restrict__ A, const ushort_t* __restrict__ BT,
    const int* __restrict__ meta, ushort_t* __restrict__ Hout,
    const int* __restrict__ perm, const float* __restrict__ prob_g,
    float* __restrict__ Yout) {
  __shared__ short A_lds[2][128 * BK];
  __shared__ short B_lds[2][128 * BK];

  int bt = blockIdx.x;               // row-tile; consecutive blocks share
  if (bt >= meta[24]) return;        //  the same B column panel (L2 reuse)
  int e    = meta[64 + bt];
  int row0 = meta[128 + bt];
  int n0   = blockIdx.y * 128;

  int tid = threadIdx.x;
  int lane = tid & 63;
  int w = tid >> 6;
  int wr = w >> 1, wc = w & 1;

  // Staging: wave w covers rows [w*32, w*32+32) of its operand tile.
  // Per instruction: 64 lanes x 16B = 16 rows; lane l -> row +(l>>2),
  // byte (l&3)*16. LDS linear [row][BK] matches base + l*16 exactly.
  const ushort_t* aBase = A + (size_t)(row0 + w * 32 + (lane >> 2)) * KDIM + (lane & 3) * 8;
  const ushort_t* bBase = BT + ((size_t)e * LDB + n0 + w * 32 + (lane >> 2)) * KDIM + (lane & 3) * 8;

#define STAGE(b, k0)                                                        \
  do {                                                                      \
    gload_lds16(aBase + (k0),                 &A_lds[b][(w * 32) * BK]);    \
    gload_lds16(aBase + (k0) + 16 * KDIM,     &A_lds[b][(w * 32 + 16) * BK]);\
    gload_lds16(bBase + (k0),                 &B_lds[b][(w * 32) * BK]);    \
    gload_lds16(bBase + (k0) + 16 * KDIM,     &B_lds[b][(w * 32 + 16) * BK]);\
  } while (0)

  f32x4 acc[4][4];
#pragma unroll
  for (int m = 0; m < 4; m++)
#pragma unroll
    for (int c = 0; c < 4; c++)
      acc[m][c] = (f32x4){0.f, 0.f, 0.f, 0.f};

  constexpr int NT = KDIM / BK;
  STAGE(0, 0);
  __syncthreads();
  int cur = 0;
  for (int t = 0; t < NT; ++t) {
    if (t + 1 < NT) STAGE(cur ^ 1, (t + 1) * BK);   // prefetch in flight
    const short* aL = A_lds[cur];
    const short* bL = B_lds[cur];
    short8 af[4], bfr[4];
#pragma unroll
    for (int m = 0; m < 4; m++)
      af[m] = *(const short8*)&aL[(wr * 64 + m * 16 + (lane & 15)) * BK + (lane >> 4) * 8];
#pragma unroll
    for (int c = 0; c < 4; c++)
      bfr[c] = *(const short8*)&bL[(wc * 64 + c * 16 + (lane & 15)) * BK + (lane >> 4) * 8];
#pragma unroll
    for (int c = 0; c < 4; c++)
#pragma unroll
      for (int m = 0; m < 4; m++)
        acc[m][c] = __builtin_amdgcn_mfma_f32_16x16x32_bf16(af[m], bfr[c], acc[m][c], 0, 0, 0);
    __syncthreads();   // drains vmcnt (stage t+1 ready) + lgkm (reads done)
    cur ^= 1;
  }
#undef STAGE

  // C/D layout (m89-verified): col = lane&15, row = (lane>>4)*4 + reg
  if constexpr (FIRST) {
#pragma unroll
    for (int m = 0; m < 4; m++) {
      int rowb = row0 + wr * 64 + m * 16 + (lane >> 4) * 4;
#pragma unroll
      for (int c = 0; c < 4; c++) {
        int col = n0 + wc * 64 + c * 16 + (lane & 15);
#pragma unroll
        for (int r = 0; r < 4; r++) {
          float v = acc[m][c][r];
          v = v > 0.f ? v : 0.f;                       // relu
          Hout[(size_t)(rowb + r) * LDB + col] = f2bf(v);
        }
      }
    }
  } else {
    int segEnd = meta[16 + e];
#pragma unroll
    for (int m = 0; m < 4; m++) {
#pragma unroll
      for (int r = 0; r < 4; r++) {
        int rg = row0 + wr * 64 + m * 16 + (lane >> 4) * 4 + r;
        if (rg < segEnd) {                             // mask pad rows
          int tok = perm[rg];
          float p = prob_g[rg];
#pragma unroll
          for (int c = 0; c < 4; c++) {
            int col = n0 + wc * 64 + c * 16 + (lane & 15);
            Yout[(size_t)tok * LDB + col] = p * acc[m][c][r];
          }
        }
      }
    }
  }
}

extern "C" void kernel_launch(void* const* d_in, const int* in_sizes, int n_in,
                              void* d_out, int out_size, void* d_ws, size_t ws_size,
                              hipStream_t stream) {
  const float* X  = (const float*)d_in[0];   // [4,1024,768]
  const float* Wr = (const float*)d_in[1];   // [768,8]
  const float* wi = (const float*)d_in[2];   // [8,768,3072]
  const float* wo = (const float*)d_in[3];   // [8,3072,768]

  float* out        = (float*)d_out;                 // [4096,768]
  float* out_logits = out + (size_t)NTOK * DM;       // [4096,8]
  float* out_idx    = out_logits + (size_t)NTOK * NE;// [4096] as float

  char* w = (char*)d_ws;
  int*      meta      = (int*)w;                        // 1 KiB
  int*      expert_of = (int*)(w + 1024);               // 16 KiB
  float*    prob      = (float*)(w + 17408);            // 16 KiB
  int*      perm      = (int*)(w + 33792);              // 20 KiB
  float*    prob_g    = (float*)(w + 54272);            // 20 KiB
  ushort_t* Xg        = (ushort_t*)(w + 74752);         // 5120*768 bf16
  ushort_t* H         = Xg + (size_t)MAXROWS * DM;      // 5120*3072 bf16
  ushort_t* wiT       = H + (size_t)MAXROWS * DF;       // 8*3072*768 bf16
  ushort_t* woT       = wiT + (size_t)NE * DF * DM;     // 8*768*3072 bf16
  // total ws: ~115 MB

  k_init<<<1, 64, 0, stream>>>(meta);
  k_convT<<<dim3(DM / 128, DF / 128, NE), 256, 0, stream>>>(wi, wiT, DM, DF);
  k_convT<<<dim3(DF / 128, DM / 128, NE), 256, 0, stream>>>(wo, woT, DF, DM);
  k_router<<<NTOK / 4, 256, 0, stream>>>(X, Wr, out_logits, out_idx,
                                         expert_of, prob, meta);
  k_scan<<<1, 64, 0, stream>>>(meta);
  k_gather<<<NTOK / 4, 256, 0, stream>>>(X, expert_of, prob, meta,
                                         perm, prob_g, Xg);
  k_gemm<DM, DF, true><<<dim3(MAXTILES, DF / 128), 256, 0, stream>>>(
      Xg, wiT, meta, H, nullptr, nullptr, nullptr);
  k_gemm<DF, DM, false><<<dim3(MAXTILES, DM / 128), 256, 0, stream>>>(
      H, woT, meta, nullptr, perm, prob_g, out);
}